// Round 11
// baseline (263.468 us; speedup 1.0000x reference)
//
#include <hip/hip_runtime.h>
#include <math.h>

#define B_  16
#define C_  512
#define A_  64
#define CV  448     // C - A (value / z_img dims)
#define G_  256
#define HW  256
#define SMX 256     // padded S (Smax)
#define BSP 8       // b-rows per block (2 blocks per group)

// ---------------- K1: spatial mean pool + per-group size ---------------------
__global__ __launch_bounds__(256) void meanpool_kernel(const float* __restrict__ Zimg,
                                                       float* __restrict__ z,
                                                       const int* __restrict__ pad_idx,
                                                       int* __restrict__ sgArr,
                                                       int Smax, int N) {
  const int bid = blockIdx.x, t = threadIdx.x;
  const int lane = t & 63, wave = t >> 6;
  __shared__ int r4[4];

  if (bid < G_) {                       // group size (prefix-contiguous validity)
    int v = pad_idx[(size_t)bid * Smax + t];
    bool ok = ((t == 0) || (v != 0)) && (v >= 0) && (v < N);
    int sgv = ok ? (t + 1) : 0;
    #pragma unroll
    for (int off = 32; off > 0; off >>= 1)
      sgv = max(sgv, __shfl_xor(sgv, off, 64));
    if (lane == 0) r4[wave] = sgv;
    __syncthreads();
    if (t == 0) sgArr[bid] = max(max(r4[0], r4[1]), max(r4[2], r4[3]));
  }

  int row = (bid << 2) + (t >> 6);      // b*C + c
  const float4* p = (const float4*)(Zimg + (size_t)row * HW);
  float4 v = p[lane];
  float s = (v.x + v.y) + (v.z + v.w);
  #pragma unroll
  for (int off = 32; off > 0; off >>= 1)
    s += __shfl_down(s, off, 64);
  if (lane == 0) z[row] = s * (1.0f / HW);
}

// ---------------- K2: bucket-rank groups by size (descending) ----------------
__global__ __launch_bounds__(256) void sched_kernel(const int* __restrict__ sgArr,
                                                    int* __restrict__ grank) {
  __shared__ int cnt[8], base[8];
  const int t = threadIdx.x;
  if (t < 8) cnt[t] = 0;
  __syncthreads();
  int sg = sgArr[t];
  int bk = min(7, max(0, sg - 32) >> 5);       // 32..256 -> 0..7
  atomicAdd(&cnt[bk], 1);
  __syncthreads();
  if (t == 0) {
    int o = 0;
    for (int b = 7; b >= 0; b--) { base[b] = o; o += cnt[b]; }
  }
  __syncthreads();
  int r = atomicAdd(&base[bk], 1);
  grank[r] = t;
}

// 8 gathered float4 loads into NAMED registers (live simultaneously).
#define GATHER8(P0,P1,P2,P3,P4,P5,P6,P7,SB) do {                           \
    const int _sb = (SB);                                                  \
    int _i0 = idxs[_sb +  0], _i1 = idxs[_sb +  4];                        \
    int _i2 = idxs[_sb +  8], _i3 = idxs[_sb + 12];                        \
    int _i4 = idxs[_sb + 16], _i5 = idxs[_sb + 20];                        \
    int _i6 = idxs[_sb + 24], _i7 = idxs[_sb + 28];                        \
    P0 = *(const float4*)(vbase + (size_t)_i0 * C_);                       \
    P1 = *(const float4*)(vbase + (size_t)_i1 * C_);                       \
    P2 = *(const float4*)(vbase + (size_t)_i2 * C_);                       \
    P3 = *(const float4*)(vbase + (size_t)_i3 * C_);                       \
    P4 = *(const float4*)(vbase + (size_t)_i4 * C_);                       \
    P5 = *(const float4*)(vbase + (size_t)_i5 * C_);                       \
    P6 = *(const float4*)(vbase + (size_t)_i6 * C_);                       \
    P7 = *(const float4*)(vbase + (size_t)_i7 * C_);                       \
  } while (0)

#define FMA1(VV, SO) do {                                                  \
    float4 _w0 = *(const float4*)(attnT + (SO) * BSP + 0);                 \
    float4 _w1 = *(const float4*)(attnT + (SO) * BSP + 4);                 \
    float4 _vv = (VV);                                                     \
    acc[0].x += _w0.x*_vv.x; acc[0].y += _w0.x*_vv.y; acc[0].z += _w0.x*_vv.z; acc[0].w += _w0.x*_vv.w; \
    acc[1].x += _w0.y*_vv.x; acc[1].y += _w0.y*_vv.y; acc[1].z += _w0.y*_vv.z; acc[1].w += _w0.y*_vv.w; \
    acc[2].x += _w0.z*_vv.x; acc[2].y += _w0.z*_vv.y; acc[2].z += _w0.z*_vv.z; acc[2].w += _w0.z*_vv.w; \
    acc[3].x += _w0.w*_vv.x; acc[3].y += _w0.w*_vv.y; acc[3].z += _w0.w*_vv.z; acc[3].w += _w0.w*_vv.w; \
    acc[4].x += _w1.x*_vv.x; acc[4].y += _w1.x*_vv.y; acc[4].z += _w1.x*_vv.z; acc[4].w += _w1.x*_vv.w; \
    acc[5].x += _w1.y*_vv.x; acc[5].y += _w1.y*_vv.y; acc[5].z += _w1.y*_vv.z; acc[5].w += _w1.y*_vv.w; \
    acc[6].x += _w1.z*_vv.x; acc[6].y += _w1.z*_vv.y; acc[6].z += _w1.z*_vv.z; acc[6].w += _w1.z*_vv.w; \
    acc[7].x += _w1.w*_vv.x; acc[7].y += _w1.w*_vv.y; acc[7].z += _w1.w*_vv.z; acc[7].w += _w1.w*_vv.w; \
  } while (0)

#define FMA8(P0,P1,P2,P3,P4,P5,P6,P7,SB) do {                              \
    FMA1(P0, (SB) +  0); FMA1(P1, (SB) +  4);                              \
    FMA1(P2, (SB) +  8); FMA1(P3, (SB) + 12);                              \
    FMA1(P4, (SB) + 16); FMA1(P5, (SB) + 20);                              \
    FMA1(P6, (SB) + 24); FMA1(P7, (SB) + 28);                              \
  } while (0)

// ---------------- K3: fused scores + softmax + PV + M_img --------------------
// Base = round-10 kernel (fused ~44us, first confirmed win: forced 8-deep
// gather pipeline). This round: cross-iteration PING-PONG PREFETCH in Phase B
// -- while FMAs consume buffer A, buffer B's 8 loads are in flight (8-16
// outstanding continuously vs 8 in bursts), per-iter cost max(L,compute)
// instead of L+compute. All guards are BLOCK-uniform (sg32) -> scalar
// branches, none of the per-lane/per-wave guard spill modes of r4/r7.
// Register budget: acc 32 + 2x v-buf 64 + addressing ~25 ~= 120 < 128 at
// launch_bounds(512,4). Spill signature (WRITE >> 14.3 MB) = falsification.
__global__ __launch_bounds__(512, 4) void fused_kernel(
    const float* __restrict__ Zsnd,
    const int*   __restrict__ pad_idx,
    const float* __restrict__ z,
    const int*   __restrict__ grank,
    float*       __restrict__ Mimg,
    float*       __restrict__ Msnd,
    int Smax, int N)
{
  const int bid  = blockIdx.x;
  const int p_   = bid & 127;
  const int bh   = (bid >> 7) & 1;
  const int rr   = (bid >> 8) ? (255 - p_) : p_;
  const int g    = grank[rr];
  const int b0   = bh * BSP;
  const int t    = threadIdx.x;
  const int lane = t & 63;
  const int wave = t >> 6;

  __shared__ float qs[BSP * A_];            // 2 KB
  __shared__ float attnT[SMX * BSP];        // 8 KB  [s][b-local]
  __shared__ int   idxs[SMX];               // 1 KB
  __shared__ float red[8 * BSP];
  __shared__ float red2[8 * BSP];
  __shared__ int   redi[8];
  __shared__ float redS[4 * BSP * 64 * 4];  // 32 KB [ch][b][lane] float4

  // ---- stage: validity/idx, queries, M_img broadcast ----
  int sgv = 0;
  if (t < SMX) {
    int v = pad_idx[(size_t)g * Smax + t];
    bool ok = ((t == 0) || (v != 0)) && (v >= 0) && (v < N);
    idxs[t] = ok ? v : 0;
    sgv = ok ? (t + 1) : 0;
  }
  #pragma unroll
  for (int off = 32; off > 0; off >>= 1)
    sgv = max(sgv, __shfl_xor(sgv, off, 64));
  if (lane == 0) redi[wave] = sgv;

  if (t < BSP * 16) {                       // 8 b x 16 a4 = 128 float4s
    int b = t >> 4, a4 = t & 15;
    *(float4*)(qs + b * A_ + a4 * 4) =
        *(const float4*)(z + (b0 + b) * C_ + CV + a4 * 4);
  }

  {                                         // Mimg[g, b0+b, :] = z[b0+b, :CV]
    int b = t >> 6, c = t & 63;
    float* mrow = Mimg + (size_t)g * (B_ * CV) + (b0 + b) * CV;
    const float* zrow = z + (b0 + b) * C_;
    *(float4*)(mrow + c * 4) = *(const float4*)(zrow + c * 4);
    int c2 = c + 64;
    if (c2 < 112)
      *(float4*)(mrow + c2 * 4) = *(const float4*)(zrow + c2 * 4);
  }

  __syncthreads();
  const int sg = max(max(max(redi[0], redi[1]), max(redi[2], redi[3])),
                     max(max(redi[4], redi[5]), max(redi[6], redi[7])));

  // ---- Phase A: scores (split-K over kh) ----
  const int s_ = t >> 1;
  const int kh = t & 1;
  const bool valid = (s_ < sg);             // prefix-contiguous validity
  const float* krow = Zsnd + (size_t)idxs[s_] * C_ + CV + kh * 32;

  float sc[BSP];
  #pragma unroll
  for (int b = 0; b < BSP; b++) sc[b] = 0.0f;

  #pragma unroll
  for (int c = 0; c < 2; c++) {
    float4 k0 = *(const float4*)(krow + c * 16 + 0);
    float4 k1 = *(const float4*)(krow + c * 16 + 4);
    float4 k2 = *(const float4*)(krow + c * 16 + 8);
    float4 k3 = *(const float4*)(krow + c * 16 + 12);
    #pragma unroll
    for (int b = 0; b < BSP; b++) {
      const float* qb = qs + b * A_ + kh * 32 + c * 16;
      float4 q0 = *(const float4*)(qb + 0);
      float4 q1 = *(const float4*)(qb + 4);
      float4 q2 = *(const float4*)(qb + 8);
      float4 q3 = *(const float4*)(qb + 12);
      sc[b] += q0.x * k0.x + q0.y * k0.y + q0.z * k0.z + q0.w * k0.w
             + q1.x * k1.x + q1.y * k1.y + q1.z * k1.z + q1.w * k1.w
             + q2.x * k2.x + q2.y * k2.y + q2.z * k2.z + q2.w * k2.w
             + q3.x * k3.x + q3.y * k3.y + q3.z * k3.z + q3.w * k3.w;
    }
    __builtin_amdgcn_sched_barrier(0);      // cap live values (anti-spill)
  }
  #pragma unroll
  for (int b = 0; b < BSP; b++)
    sc[b] += __shfl_xor(sc[b], 1, 64);      // combine kh halves: full dot

  // ---- softmax over s (butterfly within wave, LDS across 8 waves) ----
  #pragma unroll
  for (int b = 0; b < BSP; b++) {
    float v = valid ? sc[b] : -INFINITY;
    #pragma unroll
    for (int off = 32; off > 0; off >>= 1)
      v = fmaxf(v, __shfl_xor(v, off, 64));
    if (lane == 0) red[wave * BSP + b] = v;
  }
  __syncthreads();

  float ex[BSP];
  #pragma unroll
  for (int b = 0; b < BSP; b++) {
    float gm = red[0 * BSP + b];
    #pragma unroll
    for (int w2 = 1; w2 < 8; w2++) gm = fmaxf(gm, red[w2 * BSP + b]);
    float e = valid ? __expf(sc[b] - gm) : 0.0f;
    ex[b] = e;
    float es = (kh == 0) ? e : 0.0f;        // count each s once
    #pragma unroll
    for (int off = 32; off > 0; off >>= 1)
      es += __shfl_xor(es, off, 64);
    if (lane == 0) red2[wave * BSP + b] = es;
  }
  __syncthreads();

  if (kh == 0) {
    float iv[BSP];
    #pragma unroll
    for (int b = 0; b < BSP; b++) {
      float gs = red2[0 * BSP + b];
      #pragma unroll
      for (int w2 = 1; w2 < 8; w2++) gs += red2[w2 * BSP + b];
      iv[b] = ex[b] / gs;
    }
    *(float4*)(attnT + s_ * BSP + 0) = make_float4(iv[0], iv[1], iv[2], iv[3]);
    *(float4*)(attnT + s_ * BSP + 4) = make_float4(iv[4], iv[5], iv[6], iv[7]);
  }
  __syncthreads();

  // ---- Phase B: weighted value sum; ping-pong prefetched 8-deep pipeline ----
  const int ch = wave >> 1;                 // column chunk (0..3)
  const int sh = wave & 1;                  // s parity
  const int cl = lane & 31;                 // float4 column slot
  const int h  = lane >> 5;                 // s sub-parity
  const int c0 = ch * 128;
  const int sg32 = (sg + 31) & ~31;         // attnT==0 past sg -> pad is exact

  const float* vbase = Zsnd + c0 + cl * 4;  // + idx*C_ ; col <= 508 in-row
  float4 acc[BSP];
  #pragma unroll
  for (int b = 0; b < BSP; b++) acc[b] = make_float4(0.f, 0.f, 0.f, 0.f);

  const int sbase = 2 * sh + h;
  float4 a0, a1, a2, a3, a4, a5, a6, a7;    // buffer A
  float4 e0, e1, e2, e3, e4, e5, e6, e7;    // buffer B

  GATHER8(a0, a1, a2, a3, a4, a5, a6, a7, sbase);      // prologue: iter 0
  for (int s0 = 0; s0 < sg32; s0 += 64) {
    const int sb = s0 + sbase;
    if (s0 + 32 < sg32)                                // prefetch iter i+1
      GATHER8(e0, e1, e2, e3, e4, e5, e6, e7, sb + 32);
    __builtin_amdgcn_sched_barrier(0);                 // B-loads precede A-FMAs
    FMA8(a0, a1, a2, a3, a4, a5, a6, a7, sb);
    if (s0 + 64 < sg32)                                // prefetch iter i+2
      GATHER8(a0, a1, a2, a3, a4, a5, a6, a7, sb + 64);
    __builtin_amdgcn_sched_barrier(0);                 // A-loads precede B-FMAs
    if (s0 + 32 < sg32)
      FMA8(e0, e1, e2, e3, e4, e5, e6, e7, sb + 32);
  }

  // ---- cross-wave combine: sh==1 partials -> LDS, sh==0 adds + h-shfl ----
  if (sh == 1) {
    #pragma unroll
    for (int b = 0; b < BSP; b++)
      *(float4*)(redS + (((size_t)ch * BSP + b) * 64 + lane) * 4) = acc[b];
  }
  __syncthreads();
  if (sh == 0) {
    #pragma unroll
    for (int b = 0; b < BSP; b++) {
      float4 o = *(const float4*)(redS + (((size_t)ch * BSP + b) * 64 + lane) * 4);
      acc[b].x += o.x; acc[b].y += o.y; acc[b].z += o.z; acc[b].w += o.w;
      acc[b].x += __shfl_xor(acc[b].x, 32, 64);
      acc[b].y += __shfl_xor(acc[b].y, 32, 64);
      acc[b].z += __shfl_xor(acc[b].z, 32, 64);
      acc[b].w += __shfl_xor(acc[b].w, 32, 64);
    }
    if (h == 0 && c0 + cl * 4 < CV) {
      float* obase = Msnd + (size_t)g * (B_ * CV) + (size_t)b0 * CV + c0 + cl * 4;
      #pragma unroll
      for (int b = 0; b < BSP; b++)
        *(float4*)(obase + b * CV) = acc[b];
    }
  }
}

extern "C" void kernel_launch(void* const* d_in, const int* in_sizes, int n_in,
                              void* d_out, int out_size, void* d_ws, size_t ws_size,
                              hipStream_t stream) {
  const float* Zimg   = (const float*)d_in[0];
  const float* Zsnd   = (const float*)d_in[1];
  const int*   padidx = (const int*)d_in[2];
  // d_in[3] = pad_mask (unused; validity derived from pad_idx)
  // d_in[4] = attn_dims (constant 64)

  const int N    = in_sizes[1] / C_;     // rows in Z_snd
  const int Smax = in_sizes[2] / G_;     // padded sequence length (== 256)

  float* z     = (float*)d_ws;                            // B*C fp32
  int*   sgArr = (int*)(z + B_ * C_);                     // 256 ints
  int*   grank = sgArr + G_;                              // 256 ints
  float* Mimg = (float*)d_out;
  float* Msnd = Mimg + (size_t)G_ * B_ * CV;

  meanpool_kernel<<<(B_ * C_) / 4, 256, 0, stream>>>(Zimg, z, padidx, sgArr, Smax, N);
  sched_kernel<<<1, 256, 0, stream>>>(sgArr, grank);
  fused_kernel<<<G_ * 2, 512, 0, stream>>>(Zsnd, padidx, z, grank, Mimg, Msnd, Smax, N);
}

// Round 12
// 150.313 us; speedup vs baseline: 1.7528x; 1.7528x over previous
//
#include <hip/hip_runtime.h>
#include <math.h>

#define B_  16
#define C_  512
#define A_  64
#define CV  448     // C - A (value / z_img dims)
#define G_  256
#define HW  256
#define SMX 256     // padded S (Smax)
#define BSP 8       // b-rows per block (2 blocks per group)

// ---------------- K1: spatial mean pool + per-group size ---------------------
__global__ __launch_bounds__(256) void meanpool_kernel(const float* __restrict__ Zimg,
                                                       float* __restrict__ z,
                                                       const int* __restrict__ pad_idx,
                                                       int* __restrict__ sgArr,
                                                       int Smax, int N) {
  const int bid = blockIdx.x, t = threadIdx.x;
  const int lane = t & 63, wave = t >> 6;
  __shared__ int r4[4];

  if (bid < G_) {                       // group size (prefix-contiguous validity)
    int v = pad_idx[(size_t)bid * Smax + t];
    bool ok = ((t == 0) || (v != 0)) && (v >= 0) && (v < N);
    int sgv = ok ? (t + 1) : 0;
    #pragma unroll
    for (int off = 32; off > 0; off >>= 1)
      sgv = max(sgv, __shfl_xor(sgv, off, 64));
    if (lane == 0) r4[wave] = sgv;
    __syncthreads();
    if (t == 0) sgArr[bid] = max(max(r4[0], r4[1]), max(r4[2], r4[3]));
  }

  int row = (bid << 2) + (t >> 6);      // b*C + c
  const float4* p = (const float4*)(Zimg + (size_t)row * HW);
  float4 v = p[lane];
  float s = (v.x + v.y) + (v.z + v.w);
  #pragma unroll
  for (int off = 32; off > 0; off >>= 1)
    s += __shfl_down(s, off, 64);
  if (lane == 0) z[row] = s * (1.0f / HW);
}

// ---------------- K2: bucket-rank groups by size (descending) ----------------
__global__ __launch_bounds__(256) void sched_kernel(const int* __restrict__ sgArr,
                                                    int* __restrict__ grank) {
  __shared__ int cnt[8], base[8];
  const int t = threadIdx.x;
  if (t < 8) cnt[t] = 0;
  __syncthreads();
  int sg = sgArr[t];
  int bk = min(7, max(0, sg - 32) >> 5);       // 32..256 -> 0..7
  atomicAdd(&cnt[bk], 1);
  __syncthreads();
  if (t == 0) {
    int o = 0;
    for (int b = 7; b >= 0; b--) { base[b] = o; o += cnt[b]; }
  }
  __syncthreads();
  int r = atomicAdd(&base[bk], 1);
  grank[r] = t;
}

// 8 gathered float4 loads into NAMED registers (live simultaneously).
#define GATHER8(P0,P1,P2,P3,P4,P5,P6,P7,SB) do {                           \
    const int _sb = (SB);                                                  \
    int _i0 = idxs[_sb +  0], _i1 = idxs[_sb +  4];                        \
    int _i2 = idxs[_sb +  8], _i3 = idxs[_sb + 12];                        \
    int _i4 = idxs[_sb + 16], _i5 = idxs[_sb + 20];                        \
    int _i6 = idxs[_sb + 24], _i7 = idxs[_sb + 28];                        \
    P0 = *(const float4*)(vbase + (size_t)_i0 * C_);                       \
    P1 = *(const float4*)(vbase + (size_t)_i1 * C_);                       \
    P2 = *(const float4*)(vbase + (size_t)_i2 * C_);                       \
    P3 = *(const float4*)(vbase + (size_t)_i3 * C_);                       \
    P4 = *(const float4*)(vbase + (size_t)_i4 * C_);                       \
    P5 = *(const float4*)(vbase + (size_t)_i5 * C_);                       \
    P6 = *(const float4*)(vbase + (size_t)_i6 * C_);                       \
    P7 = *(const float4*)(vbase + (size_t)_i7 * C_);                       \
  } while (0)

#define FMA1(VV, SO) do {                                                  \
    float4 _w0 = *(const float4*)(attnT + (SO) * BSP + 0);                 \
    float4 _w1 = *(const float4*)(attnT + (SO) * BSP + 4);                 \
    float4 _vv = (VV);                                                     \
    acc[0].x += _w0.x*_vv.x; acc[0].y += _w0.x*_vv.y; acc[0].z += _w0.x*_vv.z; acc[0].w += _w0.x*_vv.w; \
    acc[1].x += _w0.y*_vv.x; acc[1].y += _w0.y*_vv.y; acc[1].z += _w0.y*_vv.z; acc[1].w += _w0.y*_vv.w; \
    acc[2].x += _w0.z*_vv.x; acc[2].y += _w0.z*_vv.y; acc[2].z += _w0.z*_vv.z; acc[2].w += _w0.z*_vv.w; \
    acc[3].x += _w0.w*_vv.x; acc[3].y += _w0.w*_vv.y; acc[3].z += _w0.w*_vv.z; acc[3].w += _w0.w*_vv.w; \
    acc[4].x += _w1.x*_vv.x; acc[4].y += _w1.x*_vv.y; acc[4].z += _w1.x*_vv.z; acc[4].w += _w1.x*_vv.w; \
    acc[5].x += _w1.y*_vv.x; acc[5].y += _w1.y*_vv.y; acc[5].z += _w1.y*_vv.z; acc[5].w += _w1.y*_vv.w; \
    acc[6].x += _w1.z*_vv.x; acc[6].y += _w1.z*_vv.y; acc[6].z += _w1.z*_vv.z; acc[6].w += _w1.z*_vv.w; \
    acc[7].x += _w1.w*_vv.x; acc[7].y += _w1.w*_vv.y; acc[7].z += _w1.w*_vv.z; acc[7].w += _w1.w*_vv.w; \
  } while (0)

#define FMA8(P0,P1,P2,P3,P4,P5,P6,P7,SB) do {                              \
    FMA1(P0, (SB) +  0); FMA1(P1, (SB) +  4);                              \
    FMA1(P2, (SB) +  8); FMA1(P3, (SB) + 12);                              \
    FMA1(P4, (SB) + 16); FMA1(P5, (SB) + 20);                              \
    FMA1(P6, (SB) + 24); FMA1(P7, (SB) + 28);                              \
  } while (0)

// ---------------- K3: fused scores + softmax + PV + M_img --------------------
// r10 (forced 8-deep pipeline, fused ~44us) + r11's ping-pong prefetch, with
// the register budget FIXED. Empirical launch-bounds calibration across
// r2/r6/r9/r11: VGPR cap = 2048/(arg2 x 8 waves): (512,8)->32, (512,4)->64.
// r11's ping-pong needs ~116 VGPR -> at cap 64 it spilled (VGPR 64 pinned,
// WRITE 325 MB, 161us). Fix: launch_bounds(512,2) -> cap 128. Occupancy drops
// to 16 waves/CU -- empirically free (r1/r5 @16w ~= r6 @32w ~= 53us: the
// kernel is MLP-limited, not wave-limited). Outstanding reqs/CU unchanged:
// 32w x 8 bursty (r10) -> 16w x 16 continuous.
// Phase B per iter: while FMAs consume buffer A, buffer B's 8 loads are in
// flight -> per-iter cost max(L,compute) instead of L+compute. All loop
// guards BLOCK-uniform (sg32) -> scalar branches (r4/r7 spill mode avoided).
__global__ __launch_bounds__(512, 2) void fused_kernel(
    const float* __restrict__ Zsnd,
    const int*   __restrict__ pad_idx,
    const float* __restrict__ z,
    const int*   __restrict__ grank,
    float*       __restrict__ Mimg,
    float*       __restrict__ Msnd,
    int Smax, int N)
{
  const int bid  = blockIdx.x;
  const int p_   = bid & 127;
  const int bh   = (bid >> 7) & 1;
  const int rr   = (bid >> 8) ? (255 - p_) : p_;
  const int g    = grank[rr];
  const int b0   = bh * BSP;
  const int t    = threadIdx.x;
  const int lane = t & 63;
  const int wave = t >> 6;

  __shared__ float qs[BSP * A_];            // 2 KB
  __shared__ float attnT[SMX * BSP];        // 8 KB  [s][b-local]
  __shared__ int   idxs[SMX];               // 1 KB
  __shared__ float red[8 * BSP];
  __shared__ float red2[8 * BSP];
  __shared__ int   redi[8];
  __shared__ float redS[4 * BSP * 64 * 4];  // 32 KB [ch][b][lane] float4

  // ---- stage: validity/idx, queries, M_img broadcast ----
  int sgv = 0;
  if (t < SMX) {
    int v = pad_idx[(size_t)g * Smax + t];
    bool ok = ((t == 0) || (v != 0)) && (v >= 0) && (v < N);
    idxs[t] = ok ? v : 0;
    sgv = ok ? (t + 1) : 0;
  }
  #pragma unroll
  for (int off = 32; off > 0; off >>= 1)
    sgv = max(sgv, __shfl_xor(sgv, off, 64));
  if (lane == 0) redi[wave] = sgv;

  if (t < BSP * 16) {                       // 8 b x 16 a4 = 128 float4s
    int b = t >> 4, a4 = t & 15;
    *(float4*)(qs + b * A_ + a4 * 4) =
        *(const float4*)(z + (b0 + b) * C_ + CV + a4 * 4);
  }

  {                                         // Mimg[g, b0+b, :] = z[b0+b, :CV]
    int b = t >> 6, c = t & 63;
    float* mrow = Mimg + (size_t)g * (B_ * CV) + (b0 + b) * CV;
    const float* zrow = z + (b0 + b) * C_;
    *(float4*)(mrow + c * 4) = *(const float4*)(zrow + c * 4);
    int c2 = c + 64;
    if (c2 < 112)
      *(float4*)(mrow + c2 * 4) = *(const float4*)(zrow + c2 * 4);
  }

  __syncthreads();
  const int sg = max(max(max(redi[0], redi[1]), max(redi[2], redi[3])),
                     max(max(redi[4], redi[5]), max(redi[6], redi[7])));

  // ---- Phase A: scores (split-K over kh) ----
  const int s_ = t >> 1;
  const int kh = t & 1;
  const bool valid = (s_ < sg);             // prefix-contiguous validity
  const float* krow = Zsnd + (size_t)idxs[s_] * C_ + CV + kh * 32;

  float sc[BSP];
  #pragma unroll
  for (int b = 0; b < BSP; b++) sc[b] = 0.0f;

  #pragma unroll
  for (int c = 0; c < 2; c++) {
    float4 k0 = *(const float4*)(krow + c * 16 + 0);
    float4 k1 = *(const float4*)(krow + c * 16 + 4);
    float4 k2 = *(const float4*)(krow + c * 16 + 8);
    float4 k3 = *(const float4*)(krow + c * 16 + 12);
    #pragma unroll
    for (int b = 0; b < BSP; b++) {
      const float* qb = qs + b * A_ + kh * 32 + c * 16;
      float4 q0 = *(const float4*)(qb + 0);
      float4 q1 = *(const float4*)(qb + 4);
      float4 q2 = *(const float4*)(qb + 8);
      float4 q3 = *(const float4*)(qb + 12);
      sc[b] += q0.x * k0.x + q0.y * k0.y + q0.z * k0.z + q0.w * k0.w
             + q1.x * k1.x + q1.y * k1.y + q1.z * k1.z + q1.w * k1.w
             + q2.x * k2.x + q2.y * k2.y + q2.z * k2.z + q2.w * k2.w
             + q3.x * k3.x + q3.y * k3.y + q3.z * k3.z + q3.w * k3.w;
    }
    __builtin_amdgcn_sched_barrier(0);      // cap live values (anti-spill)
  }
  #pragma unroll
  for (int b = 0; b < BSP; b++)
    sc[b] += __shfl_xor(sc[b], 1, 64);      // combine kh halves: full dot

  // ---- softmax over s (butterfly within wave, LDS across 8 waves) ----
  #pragma unroll
  for (int b = 0; b < BSP; b++) {
    float v = valid ? sc[b] : -INFINITY;
    #pragma unroll
    for (int off = 32; off > 0; off >>= 1)
      v = fmaxf(v, __shfl_xor(v, off, 64));
    if (lane == 0) red[wave * BSP + b] = v;
  }
  __syncthreads();

  float ex[BSP];
  #pragma unroll
  for (int b = 0; b < BSP; b++) {
    float gm = red[0 * BSP + b];
    #pragma unroll
    for (int w2 = 1; w2 < 8; w2++) gm = fmaxf(gm, red[w2 * BSP + b]);
    float e = valid ? __expf(sc[b] - gm) : 0.0f;
    ex[b] = e;
    float es = (kh == 0) ? e : 0.0f;        // count each s once
    #pragma unroll
    for (int off = 32; off > 0; off >>= 1)
      es += __shfl_xor(es, off, 64);
    if (lane == 0) red2[wave * BSP + b] = es;
  }
  __syncthreads();

  if (kh == 0) {
    float iv[BSP];
    #pragma unroll
    for (int b = 0; b < BSP; b++) {
      float gs = red2[0 * BSP + b];
      #pragma unroll
      for (int w2 = 1; w2 < 8; w2++) gs += red2[w2 * BSP + b];
      iv[b] = ex[b] / gs;
    }
    *(float4*)(attnT + s_ * BSP + 0) = make_float4(iv[0], iv[1], iv[2], iv[3]);
    *(float4*)(attnT + s_ * BSP + 4) = make_float4(iv[4], iv[5], iv[6], iv[7]);
  }
  __syncthreads();

  // ---- Phase B: weighted value sum; ping-pong prefetched 8-deep pipeline ----
  const int ch = wave >> 1;                 // column chunk (0..3)
  const int sh = wave & 1;                  // s parity
  const int cl = lane & 31;                 // float4 column slot
  const int h  = lane >> 5;                 // s sub-parity
  const int c0 = ch * 128;
  const int sg32 = (sg + 31) & ~31;         // attnT==0 past sg -> pad is exact

  const float* vbase = Zsnd + c0 + cl * 4;  // + idx*C_ ; col <= 508 in-row
  float4 acc[BSP];
  #pragma unroll
  for (int b = 0; b < BSP; b++) acc[b] = make_float4(0.f, 0.f, 0.f, 0.f);

  const int sbase = 2 * sh + h;
  float4 a0, a1, a2, a3, a4, a5, a6, a7;    // buffer A
  float4 e0, e1, e2, e3, e4, e5, e6, e7;    // buffer B

  GATHER8(a0, a1, a2, a3, a4, a5, a6, a7, sbase);      // prologue: iter 0
  for (int s0 = 0; s0 < sg32; s0 += 64) {
    const int sb = s0 + sbase;
    if (s0 + 32 < sg32)                                // prefetch iter i+1
      GATHER8(e0, e1, e2, e3, e4, e5, e6, e7, sb + 32);
    __builtin_amdgcn_sched_barrier(0);                 // B-loads precede A-FMAs
    FMA8(a0, a1, a2, a3, a4, a5, a6, a7, sb);
    if (s0 + 64 < sg32)                                // prefetch iter i+2
      GATHER8(a0, a1, a2, a3, a4, a5, a6, a7, sb + 64);
    __builtin_amdgcn_sched_barrier(0);                 // A-loads precede B-FMAs
    if (s0 + 32 < sg32)
      FMA8(e0, e1, e2, e3, e4, e5, e6, e7, sb + 32);
  }

  // ---- cross-wave combine: sh==1 partials -> LDS, sh==0 adds + h-shfl ----
  if (sh == 1) {
    #pragma unroll
    for (int b = 0; b < BSP; b++)
      *(float4*)(redS + (((size_t)ch * BSP + b) * 64 + lane) * 4) = acc[b];
  }
  __syncthreads();
  if (sh == 0) {
    #pragma unroll
    for (int b = 0; b < BSP; b++) {
      float4 o = *(const float4*)(redS + (((size_t)ch * BSP + b) * 64 + lane) * 4);
      acc[b].x += o.x; acc[b].y += o.y; acc[b].z += o.z; acc[b].w += o.w;
      acc[b].x += __shfl_xor(acc[b].x, 32, 64);
      acc[b].y += __shfl_xor(acc[b].y, 32, 64);
      acc[b].z += __shfl_xor(acc[b].z, 32, 64);
      acc[b].w += __shfl_xor(acc[b].w, 32, 64);
    }
    if (h == 0 && c0 + cl * 4 < CV) {
      float* obase = Msnd + (size_t)g * (B_ * CV) + (size_t)b0 * CV + c0 + cl * 4;
      #pragma unroll
      for (int b = 0; b < BSP; b++)
        *(float4*)(obase + b * CV) = acc[b];
    }
  }
}

extern "C" void kernel_launch(void* const* d_in, const int* in_sizes, int n_in,
                              void* d_out, int out_size, void* d_ws, size_t ws_size,
                              hipStream_t stream) {
  const float* Zimg   = (const float*)d_in[0];
  const float* Zsnd   = (const float*)d_in[1];
  const int*   padidx = (const int*)d_in[2];
  // d_in[3] = pad_mask (unused; validity derived from pad_idx)
  // d_in[4] = attn_dims (constant 64)

  const int N    = in_sizes[1] / C_;     // rows in Z_snd
  const int Smax = in_sizes[2] / G_;     // padded sequence length (== 256)

  float* z     = (float*)d_ws;                            // B*C fp32
  int*   sgArr = (int*)(z + B_ * C_);                     // 256 ints
  int*   grank = sgArr + G_;                              // 256 ints
  float* Mimg = (float*)d_out;
  float* Msnd = Mimg + (size_t)G_ * B_ * CV;

  meanpool_kernel<<<(B_ * C_) / 4, 256, 0, stream>>>(Zimg, z, padidx, sgArr, Smax, N);
  sched_kernel<<<1, 256, 0, stream>>>(sgArr, grank);
  fused_kernel<<<G_ * 2, 512, 0, stream>>>(Zsnd, padidx, z, grank, Mimg, Msnd, Smax, N);
}

// Round 13
// 144.145 us; speedup vs baseline: 1.8278x; 1.0428x over previous
//
#include <hip/hip_runtime.h>
#include <math.h>

#define B_  16
#define C_  512
#define A_  64
#define CV  448     // C - A (value / z_img dims)
#define G_  256
#define HW  256
#define SMX 256     // padded S (Smax)
#define BSP 8       // b-rows per block (2 blocks per group)

// ---------------- K1: spatial mean pool + per-group size ---------------------
__global__ __launch_bounds__(256) void meanpool_kernel(const float* __restrict__ Zimg,
                                                       float* __restrict__ z,
                                                       const int* __restrict__ pad_idx,
                                                       int* __restrict__ sgArr,
                                                       int Smax, int N) {
  const int bid = blockIdx.x, t = threadIdx.x;
  const int lane = t & 63, wave = t >> 6;
  __shared__ int r4[4];

  if (bid < G_) {                       // group size (prefix-contiguous validity)
    int v = pad_idx[(size_t)bid * Smax + t];
    bool ok = ((t == 0) || (v != 0)) && (v >= 0) && (v < N);
    int sgv = ok ? (t + 1) : 0;
    #pragma unroll
    for (int off = 32; off > 0; off >>= 1)
      sgv = max(sgv, __shfl_xor(sgv, off, 64));
    if (lane == 0) r4[wave] = sgv;
    __syncthreads();
    if (t == 0) sgArr[bid] = max(max(r4[0], r4[1]), max(r4[2], r4[3]));
  }

  int row = (bid << 2) + (t >> 6);      // b*C + c
  const float4* p = (const float4*)(Zimg + (size_t)row * HW);
  float4 v = p[lane];
  float s = (v.x + v.y) + (v.z + v.w);
  #pragma unroll
  for (int off = 32; off > 0; off >>= 1)
    s += __shfl_down(s, off, 64);
  if (lane == 0) z[row] = s * (1.0f / HW);
}

// ---------------- K2: bucket-rank groups by size (descending) ----------------
__global__ __launch_bounds__(256) void sched_kernel(const int* __restrict__ sgArr,
                                                    int* __restrict__ grank) {
  __shared__ int cnt[8], base[8];
  const int t = threadIdx.x;
  if (t < 8) cnt[t] = 0;
  __syncthreads();
  int sg = sgArr[t];
  int bk = min(7, max(0, sg - 32) >> 5);       // 32..256 -> 0..7
  atomicAdd(&cnt[bk], 1);
  __syncthreads();
  if (t == 0) {
    int o = 0;
    for (int b = 7; b >= 0; b--) { base[b] = o; o += cnt[b]; }
  }
  __syncthreads();
  int r = atomicAdd(&base[bk], 1);
  grank[r] = t;
}

// ---------------- K3: fused scores + softmax + PV + M_img --------------------
// Hot loop = EXACT r10 form (forced 8-deep single-buffer pipeline, (512,4),
// fused ~44us, the only confirmed structural win). One contained change:
// redS halved 32->16 KB via a TWO-PASS cross-wave combine (b 0..3 then 4..7,
// 3 barriers, all outside the hot loop). LDS 45->28.7 KB lifts occupancy
// from 3 to 4 blocks/CU (launch-bound cap): 32 waves x 8 outstanding = 256
// reqs/CU vs r10's 192. r10+r12 established outstanding-reqs/CU as the
// controlling variable (16wx16 ~= 32wx8 ~= 44-48us; Little's law at ~600ns
// L3 latency matches) -> +33% reqs predicts fused ~36-40us.
__global__ __launch_bounds__(512, 4) void fused_kernel(
    const float* __restrict__ Zsnd,
    const int*   __restrict__ pad_idx,
    const float* __restrict__ z,
    const int*   __restrict__ grank,
    float*       __restrict__ Mimg,
    float*       __restrict__ Msnd,
    int Smax, int N)
{
  const int bid  = blockIdx.x;
  const int p_   = bid & 127;
  const int bh   = (bid >> 7) & 1;
  const int rr   = (bid >> 8) ? (255 - p_) : p_;
  const int g    = grank[rr];
  const int b0   = bh * BSP;
  const int t    = threadIdx.x;
  const int lane = t & 63;
  const int wave = t >> 6;

  __shared__ float qs[BSP * A_];            // 2 KB
  __shared__ float attnT[SMX * BSP];        // 8 KB  [s][b-local]
  __shared__ int   idxs[SMX];               // 1 KB
  __shared__ float red[8 * BSP];
  __shared__ float red2[8 * BSP];
  __shared__ int   redi[8];
  __shared__ float redS[4 * 4 * 64 * 4];    // 16 KB [ch][b-quad][lane] float4

  // ---- stage: validity/idx, queries, M_img broadcast ----
  int sgv = 0;
  if (t < SMX) {
    int v = pad_idx[(size_t)g * Smax + t];
    bool ok = ((t == 0) || (v != 0)) && (v >= 0) && (v < N);
    idxs[t] = ok ? v : 0;
    sgv = ok ? (t + 1) : 0;
  }
  #pragma unroll
  for (int off = 32; off > 0; off >>= 1)
    sgv = max(sgv, __shfl_xor(sgv, off, 64));
  if (lane == 0) redi[wave] = sgv;

  if (t < BSP * 16) {                       // 8 b x 16 a4 = 128 float4s
    int b = t >> 4, a4 = t & 15;
    *(float4*)(qs + b * A_ + a4 * 4) =
        *(const float4*)(z + (b0 + b) * C_ + CV + a4 * 4);
  }

  {                                         // Mimg[g, b0+b, :] = z[b0+b, :CV]
    int b = t >> 6, c = t & 63;
    float* mrow = Mimg + (size_t)g * (B_ * CV) + (b0 + b) * CV;
    const float* zrow = z + (b0 + b) * C_;
    *(float4*)(mrow + c * 4) = *(const float4*)(zrow + c * 4);
    int c2 = c + 64;
    if (c2 < 112)
      *(float4*)(mrow + c2 * 4) = *(const float4*)(zrow + c2 * 4);
  }

  __syncthreads();
  const int sg = max(max(max(redi[0], redi[1]), max(redi[2], redi[3])),
                     max(max(redi[4], redi[5]), max(redi[6], redi[7])));

  // ---- Phase A: scores (split-K over kh) ----
  const int s_ = t >> 1;
  const int kh = t & 1;
  const bool valid = (s_ < sg);             // prefix-contiguous validity
  const float* krow = Zsnd + (size_t)idxs[s_] * C_ + CV + kh * 32;

  float sc[BSP];
  #pragma unroll
  for (int b = 0; b < BSP; b++) sc[b] = 0.0f;

  #pragma unroll
  for (int c = 0; c < 2; c++) {
    float4 k0 = *(const float4*)(krow + c * 16 + 0);
    float4 k1 = *(const float4*)(krow + c * 16 + 4);
    float4 k2 = *(const float4*)(krow + c * 16 + 8);
    float4 k3 = *(const float4*)(krow + c * 16 + 12);
    #pragma unroll
    for (int b = 0; b < BSP; b++) {
      const float* qb = qs + b * A_ + kh * 32 + c * 16;
      float4 q0 = *(const float4*)(qb + 0);
      float4 q1 = *(const float4*)(qb + 4);
      float4 q2 = *(const float4*)(qb + 8);
      float4 q3 = *(const float4*)(qb + 12);
      sc[b] += q0.x * k0.x + q0.y * k0.y + q0.z * k0.z + q0.w * k0.w
             + q1.x * k1.x + q1.y * k1.y + q1.z * k1.z + q1.w * k1.w
             + q2.x * k2.x + q2.y * k2.y + q2.z * k2.z + q2.w * k2.w
             + q3.x * k3.x + q3.y * k3.y + q3.z * k3.z + q3.w * k3.w;
    }
    __builtin_amdgcn_sched_barrier(0);      // cap live values (anti-spill)
  }
  #pragma unroll
  for (int b = 0; b < BSP; b++)
    sc[b] += __shfl_xor(sc[b], 1, 64);      // combine kh halves: full dot

  // ---- softmax over s (butterfly within wave, LDS across 8 waves) ----
  #pragma unroll
  for (int b = 0; b < BSP; b++) {
    float v = valid ? sc[b] : -INFINITY;
    #pragma unroll
    for (int off = 32; off > 0; off >>= 1)
      v = fmaxf(v, __shfl_xor(v, off, 64));
    if (lane == 0) red[wave * BSP + b] = v;
  }
  __syncthreads();

  float ex[BSP];
  #pragma unroll
  for (int b = 0; b < BSP; b++) {
    float gm = red[0 * BSP + b];
    #pragma unroll
    for (int w2 = 1; w2 < 8; w2++) gm = fmaxf(gm, red[w2 * BSP + b]);
    float e = valid ? __expf(sc[b] - gm) : 0.0f;
    ex[b] = e;
    float es = (kh == 0) ? e : 0.0f;        // count each s once
    #pragma unroll
    for (int off = 32; off > 0; off >>= 1)
      es += __shfl_xor(es, off, 64);
    if (lane == 0) red2[wave * BSP + b] = es;
  }
  __syncthreads();

  if (kh == 0) {
    float iv[BSP];
    #pragma unroll
    for (int b = 0; b < BSP; b++) {
      float gs = red2[0 * BSP + b];
      #pragma unroll
      for (int w2 = 1; w2 < 8; w2++) gs += red2[w2 * BSP + b];
      iv[b] = ex[b] / gs;
    }
    *(float4*)(attnT + s_ * BSP + 0) = make_float4(iv[0], iv[1], iv[2], iv[3]);
    *(float4*)(attnT + s_ * BSP + 4) = make_float4(iv[4], iv[5], iv[6], iv[7]);
  }
  __syncthreads();

  // ---- Phase B: weighted value sum; FORCED 8-deep gather pipeline (r10) ----
  const int ch = wave >> 1;                 // column chunk (0..3)
  const int sh = wave & 1;                  // s parity
  const int cl = lane & 31;                 // float4 column slot
  const int h  = lane >> 5;                 // s sub-parity
  const int c0 = ch * 128;
  const int sg32 = (sg + 31) & ~31;         // attnT==0 past sg -> pad is exact

  const float* vbase = Zsnd + c0 + cl * 4;  // + idx*C_ ; col <= 508 in-row
  float4 acc[BSP];
  #pragma unroll
  for (int b = 0; b < BSP; b++) acc[b] = make_float4(0.f, 0.f, 0.f, 0.f);

  for (int s0 = 0; s0 < sg32; s0 += 32) {
    const int sb = s0 + 2 * sh + h;
    // hoisted LDS idx reads (batched ds_read, one lgkm wait)
    int i0 = idxs[sb +  0], i1 = idxs[sb +  4], i2 = idxs[sb +  8], i3 = idxs[sb + 12];
    int i4 = idxs[sb + 16], i5 = idxs[sb + 20], i6 = idxs[sb + 24], i7 = idxs[sb + 28];
    // 8 loads issued back-to-back into NAMED values; all live at the barrier
    float4 v0 = *(const float4*)(vbase + (size_t)i0 * C_);
    float4 v1 = *(const float4*)(vbase + (size_t)i1 * C_);
    float4 v2 = *(const float4*)(vbase + (size_t)i2 * C_);
    float4 v3 = *(const float4*)(vbase + (size_t)i3 * C_);
    float4 v4 = *(const float4*)(vbase + (size_t)i4 * C_);
    float4 v5 = *(const float4*)(vbase + (size_t)i5 * C_);
    float4 v6 = *(const float4*)(vbase + (size_t)i6 * C_);
    float4 v7 = *(const float4*)(vbase + (size_t)i7 * C_);
    __builtin_amdgcn_sched_barrier(0);      // loads may NOT sink past this
    #pragma unroll
    for (int j = 0; j < 8; j++) {
      float4 vv = (j == 0) ? v0 : (j == 1) ? v1 : (j == 2) ? v2 : (j == 3) ? v3
                : (j == 4) ? v4 : (j == 5) ? v5 : (j == 6) ? v6 : v7;
      int so = sb + 4 * j;
      float4 w0 = *(const float4*)(attnT + so * BSP + 0);   // b 0..3 (broadcast)
      float4 w1 = *(const float4*)(attnT + so * BSP + 4);   // b 4..7
      acc[0].x += w0.x * vv.x; acc[0].y += w0.x * vv.y; acc[0].z += w0.x * vv.z; acc[0].w += w0.x * vv.w;
      acc[1].x += w0.y * vv.x; acc[1].y += w0.y * vv.y; acc[1].z += w0.y * vv.z; acc[1].w += w0.y * vv.w;
      acc[2].x += w0.z * vv.x; acc[2].y += w0.z * vv.y; acc[2].z += w0.z * vv.z; acc[2].w += w0.z * vv.w;
      acc[3].x += w0.w * vv.x; acc[3].y += w0.w * vv.y; acc[3].z += w0.w * vv.z; acc[3].w += w0.w * vv.w;
      acc[4].x += w1.x * vv.x; acc[4].y += w1.x * vv.y; acc[4].z += w1.x * vv.z; acc[4].w += w1.x * vv.w;
      acc[5].x += w1.y * vv.x; acc[5].y += w1.y * vv.y; acc[5].z += w1.y * vv.z; acc[5].w += w1.y * vv.w;
      acc[6].x += w1.z * vv.x; acc[6].y += w1.z * vv.y; acc[6].z += w1.z * vv.z; acc[6].w += w1.z * vv.w;
      acc[7].x += w1.w * vv.x; acc[7].y += w1.w * vv.y; acc[7].z += w1.w * vv.z; acc[7].w += w1.w * vv.w;
    }
  }

  // ---- cross-wave combine: TWO PASSES of 4 b-rows through 16 KB redS ----
  // pass 1: b = 0..3
  if (sh == 1) {
    #pragma unroll
    for (int b = 0; b < 4; b++)
      *(float4*)(redS + (((size_t)ch * 4 + b) * 64 + lane) * 4) = acc[b];
  }
  __syncthreads();
  if (sh == 0) {
    #pragma unroll
    for (int b = 0; b < 4; b++) {
      float4 o = *(const float4*)(redS + (((size_t)ch * 4 + b) * 64 + lane) * 4);
      acc[b].x += o.x; acc[b].y += o.y; acc[b].z += o.z; acc[b].w += o.w;
      acc[b].x += __shfl_xor(acc[b].x, 32, 64);
      acc[b].y += __shfl_xor(acc[b].y, 32, 64);
      acc[b].z += __shfl_xor(acc[b].z, 32, 64);
      acc[b].w += __shfl_xor(acc[b].w, 32, 64);
    }
  }
  __syncthreads();
  // pass 2: b = 4..7
  if (sh == 1) {
    #pragma unroll
    for (int b = 4; b < 8; b++)
      *(float4*)(redS + (((size_t)ch * 4 + (b - 4)) * 64 + lane) * 4) = acc[b];
  }
  __syncthreads();
  if (sh == 0) {
    #pragma unroll
    for (int b = 4; b < 8; b++) {
      float4 o = *(const float4*)(redS + (((size_t)ch * 4 + (b - 4)) * 64 + lane) * 4);
      acc[b].x += o.x; acc[b].y += o.y; acc[b].z += o.z; acc[b].w += o.w;
      acc[b].x += __shfl_xor(acc[b].x, 32, 64);
      acc[b].y += __shfl_xor(acc[b].y, 32, 64);
      acc[b].z += __shfl_xor(acc[b].z, 32, 64);
      acc[b].w += __shfl_xor(acc[b].w, 32, 64);
    }
    if (h == 0 && c0 + cl * 4 < CV) {
      float* obase = Msnd + (size_t)g * (B_ * CV) + (size_t)b0 * CV + c0 + cl * 4;
      #pragma unroll
      for (int b = 0; b < BSP; b++)
        *(float4*)(obase + b * CV) = acc[b];
    }
  }
}

extern "C" void kernel_launch(void* const* d_in, const int* in_sizes, int n_in,
                              void* d_out, int out_size, void* d_ws, size_t ws_size,
                              hipStream_t stream) {
  const float* Zimg   = (const float*)d_in[0];
  const float* Zsnd   = (const float*)d_in[1];
  const int*   padidx = (const int*)d_in[2];
  // d_in[3] = pad_mask (unused; validity derived from pad_idx)
  // d_in[4] = attn_dims (constant 64)

  const int N    = in_sizes[1] / C_;     // rows in Z_snd
  const int Smax = in_sizes[2] / G_;     // padded sequence length (== 256)

  float* z     = (float*)d_ws;                            // B*C fp32
  int*   sgArr = (int*)(z + B_ * C_);                     // 256 ints
  int*   grank = sgArr + G_;                              // 256 ints
  float* Mimg = (float*)d_out;
  float* Msnd = Mimg + (size_t)G_ * B_ * CV;

  meanpool_kernel<<<(B_ * C_) / 4, 256, 0, stream>>>(Zimg, z, padidx, sgArr, Smax, N);
  sched_kernel<<<1, 256, 0, stream>>>(sgArr, grank);
  fused_kernel<<<G_ * 2, 512, 0, stream>>>(Zsnd, padidx, z, grank, Mimg, Msnd, Smax, N);
}

// Round 14
// 143.867 us; speedup vs baseline: 1.8313x; 1.0019x over previous
//
#include <hip/hip_runtime.h>
#include <math.h>

#define B_  16
#define C_  512
#define A_  64
#define CV  448     // C - A (value / z_img dims)
#define G_  256
#define HW  256
#define SMX 256     // padded S (Smax)
#define BSP 8       // b-rows per block (2 blocks per group)

// ---------------- K1: spatial mean pool + per-group size ---------------------
__global__ __launch_bounds__(256) void meanpool_kernel(const float* __restrict__ Zimg,
                                                       float* __restrict__ z,
                                                       const int* __restrict__ pad_idx,
                                                       int* __restrict__ sgArr,
                                                       int Smax, int N) {
  const int bid = blockIdx.x, t = threadIdx.x;
  const int lane = t & 63, wave = t >> 6;
  __shared__ int r4[4];

  if (bid < G_) {                       // group size (prefix-contiguous validity)
    int v = pad_idx[(size_t)bid * Smax + t];
    bool ok = ((t == 0) || (v != 0)) && (v >= 0) && (v < N);
    int sgv = ok ? (t + 1) : 0;
    #pragma unroll
    for (int off = 32; off > 0; off >>= 1)
      sgv = max(sgv, __shfl_xor(sgv, off, 64));
    if (lane == 0) r4[wave] = sgv;
    __syncthreads();
    if (t == 0) sgArr[bid] = max(max(r4[0], r4[1]), max(r4[2], r4[3]));
  }

  int row = (bid << 2) + (t >> 6);      // b*C + c
  const float4* p = (const float4*)(Zimg + (size_t)row * HW);
  float4 v = p[lane];
  float s = (v.x + v.y) + (v.z + v.w);
  #pragma unroll
  for (int off = 32; off > 0; off >>= 1)
    s += __shfl_down(s, off, 64);
  if (lane == 0) z[row] = s * (1.0f / HW);
}

// ---------------- K2: bucket-rank groups by size (descending) ----------------
__global__ __launch_bounds__(256) void sched_kernel(const int* __restrict__ sgArr,
                                                    int* __restrict__ grank) {
  __shared__ int cnt[8], base[8];
  const int t = threadIdx.x;
  if (t < 8) cnt[t] = 0;
  __syncthreads();
  int sg = sgArr[t];
  int bk = min(7, max(0, sg - 32) >> 5);       // 32..256 -> 0..7
  atomicAdd(&cnt[bk], 1);
  __syncthreads();
  if (t == 0) {
    int o = 0;
    for (int b = 7; b >= 0; b--) { base[b] = o; o += cnt[b]; }
  }
  __syncthreads();
  int r = atomicAdd(&base[bk], 1);
  grank[r] = t;
}

// ---------------- K3: fused scores + softmax + PV + M_img --------------------
// = r13 kernel (fused ~41us: forced 8-deep pipeline + 16 KB redS two-pass
// combine, 4 blocks/CU = 256 outstanding reqs/CU) with ONE byte-reduction:
// column-chunk 3 covers cols 384..511 but only 384..447 are real (CV=448).
// Lanes 28..31 fetched 2 dead 128B lines per value row = 12.5% of value
// traffic. Fix: branchless clamp cle=min(cl,27) for ch3 -- clamped lanes
// re-read lane 27's line (L1-dedup, no extra lines), stores already guarded
// by c0+cl*4<CV, cross-wave combine is lane-symmetric (garbage never stored).
__global__ __launch_bounds__(512, 4) void fused_kernel(
    const float* __restrict__ Zsnd,
    const int*   __restrict__ pad_idx,
    const float* __restrict__ z,
    const int*   __restrict__ grank,
    float*       __restrict__ Mimg,
    float*       __restrict__ Msnd,
    int Smax, int N)
{
  const int bid  = blockIdx.x;
  const int p_   = bid & 127;
  const int bh   = (bid >> 7) & 1;
  const int rr   = (bid >> 8) ? (255 - p_) : p_;
  const int g    = grank[rr];
  const int b0   = bh * BSP;
  const int t    = threadIdx.x;
  const int lane = t & 63;
  const int wave = t >> 6;

  __shared__ float qs[BSP * A_];            // 2 KB
  __shared__ float attnT[SMX * BSP];        // 8 KB  [s][b-local]
  __shared__ int   idxs[SMX];               // 1 KB
  __shared__ float red[8 * BSP];
  __shared__ float red2[8 * BSP];
  __shared__ int   redi[8];
  __shared__ float redS[4 * 4 * 64 * 4];    // 16 KB [ch][b-quad][lane] float4

  // ---- stage: validity/idx, queries, M_img broadcast ----
  int sgv = 0;
  if (t < SMX) {
    int v = pad_idx[(size_t)g * Smax + t];
    bool ok = ((t == 0) || (v != 0)) && (v >= 0) && (v < N);
    idxs[t] = ok ? v : 0;
    sgv = ok ? (t + 1) : 0;
  }
  #pragma unroll
  for (int off = 32; off > 0; off >>= 1)
    sgv = max(sgv, __shfl_xor(sgv, off, 64));
  if (lane == 0) redi[wave] = sgv;

  if (t < BSP * 16) {                       // 8 b x 16 a4 = 128 float4s
    int b = t >> 4, a4 = t & 15;
    *(float4*)(qs + b * A_ + a4 * 4) =
        *(const float4*)(z + (b0 + b) * C_ + CV + a4 * 4);
  }

  {                                         // Mimg[g, b0+b, :] = z[b0+b, :CV]
    int b = t >> 6, c = t & 63;
    float* mrow = Mimg + (size_t)g * (B_ * CV) + (b0 + b) * CV;
    const float* zrow = z + (b0 + b) * C_;
    *(float4*)(mrow + c * 4) = *(const float4*)(zrow + c * 4);
    int c2 = c + 64;
    if (c2 < 112)
      *(float4*)(mrow + c2 * 4) = *(const float4*)(zrow + c2 * 4);
  }

  __syncthreads();
  const int sg = max(max(max(redi[0], redi[1]), max(redi[2], redi[3])),
                     max(max(redi[4], redi[5]), max(redi[6], redi[7])));

  // ---- Phase A: scores (split-K over kh) ----
  const int s_ = t >> 1;
  const int kh = t & 1;
  const bool valid = (s_ < sg);             // prefix-contiguous validity
  const float* krow = Zsnd + (size_t)idxs[s_] * C_ + CV + kh * 32;

  float sc[BSP];
  #pragma unroll
  for (int b = 0; b < BSP; b++) sc[b] = 0.0f;

  #pragma unroll
  for (int c = 0; c < 2; c++) {
    float4 k0 = *(const float4*)(krow + c * 16 + 0);
    float4 k1 = *(const float4*)(krow + c * 16 + 4);
    float4 k2 = *(const float4*)(krow + c * 16 + 8);
    float4 k3 = *(const float4*)(krow + c * 16 + 12);
    #pragma unroll
    for (int b = 0; b < BSP; b++) {
      const float* qb = qs + b * A_ + kh * 32 + c * 16;
      float4 q0 = *(const float4*)(qb + 0);
      float4 q1 = *(const float4*)(qb + 4);
      float4 q2 = *(const float4*)(qb + 8);
      float4 q3 = *(const float4*)(qb + 12);
      sc[b] += q0.x * k0.x + q0.y * k0.y + q0.z * k0.z + q0.w * k0.w
             + q1.x * k1.x + q1.y * k1.y + q1.z * k1.z + q1.w * k1.w
             + q2.x * k2.x + q2.y * k2.y + q2.z * k2.z + q2.w * k2.w
             + q3.x * k3.x + q3.y * k3.y + q3.z * k3.z + q3.w * k3.w;
    }
    __builtin_amdgcn_sched_barrier(0);      // cap live values (anti-spill)
  }
  #pragma unroll
  for (int b = 0; b < BSP; b++)
    sc[b] += __shfl_xor(sc[b], 1, 64);      // combine kh halves: full dot

  // ---- softmax over s (butterfly within wave, LDS across 8 waves) ----
  #pragma unroll
  for (int b = 0; b < BSP; b++) {
    float v = valid ? sc[b] : -INFINITY;
    #pragma unroll
    for (int off = 32; off > 0; off >>= 1)
      v = fmaxf(v, __shfl_xor(v, off, 64));
    if (lane == 0) red[wave * BSP + b] = v;
  }
  __syncthreads();

  float ex[BSP];
  #pragma unroll
  for (int b = 0; b < BSP; b++) {
    float gm = red[0 * BSP + b];
    #pragma unroll
    for (int w2 = 1; w2 < 8; w2++) gm = fmaxf(gm, red[w2 * BSP + b]);
    float e = valid ? __expf(sc[b] - gm) : 0.0f;
    ex[b] = e;
    float es = (kh == 0) ? e : 0.0f;        // count each s once
    #pragma unroll
    for (int off = 32; off > 0; off >>= 1)
      es += __shfl_xor(es, off, 64);
    if (lane == 0) red2[wave * BSP + b] = es;
  }
  __syncthreads();

  if (kh == 0) {
    float iv[BSP];
    #pragma unroll
    for (int b = 0; b < BSP; b++) {
      float gs = red2[0 * BSP + b];
      #pragma unroll
      for (int w2 = 1; w2 < 8; w2++) gs += red2[w2 * BSP + b];
      iv[b] = ex[b] / gs;
    }
    *(float4*)(attnT + s_ * BSP + 0) = make_float4(iv[0], iv[1], iv[2], iv[3]);
    *(float4*)(attnT + s_ * BSP + 4) = make_float4(iv[4], iv[5], iv[6], iv[7]);
  }
  __syncthreads();

  // ---- Phase B: weighted value sum; FORCED 8-deep gather pipeline (r10) ----
  const int ch = wave >> 1;                 // column chunk (0..3)
  const int sh = wave & 1;                  // s parity
  const int cl = lane & 31;                 // float4 column slot
  const int h  = lane >> 5;                 // s sub-parity
  const int c0 = ch * 128;
  const int cle = (ch == 3) ? min(cl, 27) : cl;   // ch3: skip dead cols >= CV
  const int sg32 = (sg + 31) & ~31;         // attnT==0 past sg -> pad is exact

  const float* vbase = Zsnd + c0 + cle * 4; // + idx*C_ ; col <= 508 in-row
  float4 acc[BSP];
  #pragma unroll
  for (int b = 0; b < BSP; b++) acc[b] = make_float4(0.f, 0.f, 0.f, 0.f);

  for (int s0 = 0; s0 < sg32; s0 += 32) {
    const int sb = s0 + 2 * sh + h;
    // hoisted LDS idx reads (batched ds_read, one lgkm wait)
    int i0 = idxs[sb +  0], i1 = idxs[sb +  4], i2 = idxs[sb +  8], i3 = idxs[sb + 12];
    int i4 = idxs[sb + 16], i5 = idxs[sb + 20], i6 = idxs[sb + 24], i7 = idxs[sb + 28];
    // 8 loads issued back-to-back into NAMED values; all live at the barrier
    float4 v0 = *(const float4*)(vbase + (size_t)i0 * C_);
    float4 v1 = *(const float4*)(vbase + (size_t)i1 * C_);
    float4 v2 = *(const float4*)(vbase + (size_t)i2 * C_);
    float4 v3 = *(const float4*)(vbase + (size_t)i3 * C_);
    float4 v4 = *(const float4*)(vbase + (size_t)i4 * C_);
    float4 v5 = *(const float4*)(vbase + (size_t)i5 * C_);
    float4 v6 = *(const float4*)(vbase + (size_t)i6 * C_);
    float4 v7 = *(const float4*)(vbase + (size_t)i7 * C_);
    __builtin_amdgcn_sched_barrier(0);      // loads may NOT sink past this
    #pragma unroll
    for (int j = 0; j < 8; j++) {
      float4 vv = (j == 0) ? v0 : (j == 1) ? v1 : (j == 2) ? v2 : (j == 3) ? v3
                : (j == 4) ? v4 : (j == 5) ? v5 : (j == 6) ? v6 : v7;
      int so = sb + 4 * j;
      float4 w0 = *(const float4*)(attnT + so * BSP + 0);   // b 0..3 (broadcast)
      float4 w1 = *(const float4*)(attnT + so * BSP + 4);   // b 4..7
      acc[0].x += w0.x * vv.x; acc[0].y += w0.x * vv.y; acc[0].z += w0.x * vv.z; acc[0].w += w0.x * vv.w;
      acc[1].x += w0.y * vv.x; acc[1].y += w0.y * vv.y; acc[1].z += w0.y * vv.z; acc[1].w += w0.y * vv.w;
      acc[2].x += w0.z * vv.x; acc[2].y += w0.z * vv.y; acc[2].z += w0.z * vv.z; acc[2].w += w0.z * vv.w;
      acc[3].x += w0.w * vv.x; acc[3].y += w0.w * vv.y; acc[3].z += w0.w * vv.z; acc[3].w += w0.w * vv.w;
      acc[4].x += w1.x * vv.x; acc[4].y += w1.x * vv.y; acc[4].z += w1.x * vv.z; acc[4].w += w1.x * vv.w;
      acc[5].x += w1.y * vv.x; acc[5].y += w1.y * vv.y; acc[5].z += w1.y * vv.z; acc[5].w += w1.y * vv.w;
      acc[6].x += w1.z * vv.x; acc[6].y += w1.z * vv.y; acc[6].z += w1.z * vv.z; acc[6].w += w1.z * vv.w;
      acc[7].x += w1.w * vv.x; acc[7].y += w1.w * vv.y; acc[7].z += w1.w * vv.z; acc[7].w += w1.w * vv.w;
    }
  }

  // ---- cross-wave combine: TWO PASSES of 4 b-rows through 16 KB redS ----
  // pass 1: b = 0..3
  if (sh == 1) {
    #pragma unroll
    for (int b = 0; b < 4; b++)
      *(float4*)(redS + (((size_t)ch * 4 + b) * 64 + lane) * 4) = acc[b];
  }
  __syncthreads();
  if (sh == 0) {
    #pragma unroll
    for (int b = 0; b < 4; b++) {
      float4 o = *(const float4*)(redS + (((size_t)ch * 4 + b) * 64 + lane) * 4);
      acc[b].x += o.x; acc[b].y += o.y; acc[b].z += o.z; acc[b].w += o.w;
      acc[b].x += __shfl_xor(acc[b].x, 32, 64);
      acc[b].y += __shfl_xor(acc[b].y, 32, 64);
      acc[b].z += __shfl_xor(acc[b].z, 32, 64);
      acc[b].w += __shfl_xor(acc[b].w, 32, 64);
    }
  }
  __syncthreads();
  // pass 2: b = 4..7
  if (sh == 1) {
    #pragma unroll
    for (int b = 4; b < 8; b++)
      *(float4*)(redS + (((size_t)ch * 4 + (b - 4)) * 64 + lane) * 4) = acc[b];
  }
  __syncthreads();
  if (sh == 0) {
    #pragma unroll
    for (int b = 4; b < 8; b++) {
      float4 o = *(const float4*)(redS + (((size_t)ch * 4 + (b - 4)) * 64 + lane) * 4);
      acc[b].x += o.x; acc[b].y += o.y; acc[b].z += o.z; acc[b].w += o.w;
      acc[b].x += __shfl_xor(acc[b].x, 32, 64);
      acc[b].y += __shfl_xor(acc[b].y, 32, 64);
      acc[b].z += __shfl_xor(acc[b].z, 32, 64);
      acc[b].w += __shfl_xor(acc[b].w, 32, 64);
    }
    if (h == 0 && c0 + cl * 4 < CV) {
      float* obase = Msnd + (size_t)g * (B_ * CV) + (size_t)b0 * CV + c0 + cl * 4;
      #pragma unroll
      for (int b = 0; b < BSP; b++)
        *(float4*)(obase + b * CV) = acc[b];
    }
  }
}

extern "C" void kernel_launch(void* const* d_in, const int* in_sizes, int n_in,
                              void* d_out, int out_size, void* d_ws, size_t ws_size,
                              hipStream_t stream) {
  const float* Zimg   = (const float*)d_in[0];
  const float* Zsnd   = (const float*)d_in[1];
  const int*   padidx = (const int*)d_in[2];
  // d_in[3] = pad_mask (unused; validity derived from pad_idx)
  // d_in[4] = attn_dims (constant 64)

  const int N    = in_sizes[1] / C_;     // rows in Z_snd
  const int Smax = in_sizes[2] / G_;     // padded sequence length (== 256)

  float* z     = (float*)d_ws;                            // B*C fp32
  int*   sgArr = (int*)(z + B_ * C_);                     // 256 ints
  int*   grank = sgArr + G_;                              // 256 ints
  float* Mimg = (float*)d_out;
  float* Msnd = Mimg + (size_t)G_ * B_ * CV;

  meanpool_kernel<<<(B_ * C_) / 4, 256, 0, stream>>>(Zimg, z, padidx, sgArr, Smax, N);
  sched_kernel<<<1, 256, 0, stream>>>(sgArr, grank);
  fused_kernel<<<G_ * 2, 512, 0, stream>>>(Zsnd, padidx, z, grank, Mimg, Msnd, Smax, N);
}